// Round 22
// baseline (75.659 us; speedup 1.0000x reference)
//
#include <hip/hip_runtime.h>
#include <stdint.h>

#define NPIX   16384
#define KC     8192
#define DD     64
#define EMS    8193          // embed row stride (K+1)
#define OUT_QUANT 0
#define OUT_DMIN  1048576
#define OUT_IND   (1048576 + 16384)

typedef _Float16 f16;
typedef _Float16 f16x8 __attribute__((ext_vector_type(8)));
typedef float    f32x4 __attribute__((ext_vector_type(4)));
typedef unsigned long long u64;

// async global->LDS, 16B/lane; dest = wave-uniform base (+lane*16 by HW)
__device__ __forceinline__ void gld_lds16(const void* g, void* l) {
    __builtin_amdgcn_global_load_lds(
        (const __attribute__((address_space(1))) uint32_t*)g,
        (__attribute__((address_space(3))) uint32_t*)l, 16, 0, 0);
}

// ---------------------------------------------------------------------------
// Fused prep, parallelized over (slot, element): 768 blocks.
// Blocks 0..511   : x -> f16 HI A3[8][NPIX][8]   (thread = one (s,n))
// Blocks 512..767 : embed -> f16 hi/lo B3[16][KC][8] (thread = one (s,k));
//                   the s==0 slice also computes masked +1024-biased norms.
// ---------------------------------------------------------------------------
__global__ __launch_bounds__(256)
void vq_prep(const float* __restrict__ x, const float* __restrict__ em,
             const int* __restrict__ cnt,
             f16* __restrict__ A3, f16* __restrict__ B3,
             float* __restrict__ cn) {
    const int b = blockIdx.x;
    if (b < 512) {
        int id = b * 256 + threadIdx.x;      // (s,n)
        int n = id & (NPIX - 1);
        int s = id >> 14;
        f16x8 hv;
#pragma unroll
        for (int j = 0; j < 8; ++j)
            hv[j] = (f16)x[(s * 8 + j) * NPIX + n];
        *(f16x8*)&A3[((u64)s * NPIX + n) * 8] = hv;
    } else {
        int id = (b - 512) * 256 + threadIdx.x;   // (s,k)
        int k = id & (KC - 1);
        int s = id >> 13;
        f16x8 hv, lv;
#pragma unroll
        for (int j = 0; j < 8; ++j) {
            float v = em[(s * 8 + j) * EMS + k];
            f16 h = (f16)v;
            hv[j] = h;
            lv[j] = (f16)(v - (float)h);
        }
        *(f16x8*)&B3[((u64)(s)     * KC + k) * 8] = hv;
        *(f16x8*)&B3[((u64)(s + 8) * KC + k) * 8] = lv;
        if (s == 0) {
            float s2 = 0.f;
#pragma unroll
            for (int d = 0; d < DD; ++d) {
                float v = em[d * EMS + k];
                s2 = fmaf(v, v, s2);
            }
            cn[k] = (cnt[k] < 1) ? 1.0e30f : (s2 + 1024.f);
        }
    }
}

// ---------------------------------------------------------------------------
// MFMA distance GEMM + fused per-block argmin, 2-phase pipelined.
// Product: Xh.E = Xh.Eh + Xh.El  -> 4 K-steps of 32 (K=128).
// Block: 256 pixels x 512 codes, 8 ns-subtiles of 64 codes.
// Wave w owns 64 ROWS (4 m-blocks): each bf LDS read feeds 4 MFMAs.
// REGISTER FIT (R20+R21 lessons): each ns is processed in TWO n-halves so
// the live accumulator is acc[4][2] = 32 AGPR; with ~72 VGPR the unified
// total ~104 fits launch_bounds(256,4)'s 128-reg cap -> 4 blocks/CU, and
// grid 1024 = 256 CUs x 4 = ONE exact generation (the R21 flat result was
// 1024 blocks at 3/CU = ragged 2-generation wall).
// A-frags from one-time global prologue; B double-buffered in LDS;
// kt=0 MFMAs take zero4 as C-in; packed slot-in-mantissa fminf min.
// ---------------------------------------------------------------------------
__global__ __launch_bounds__(256, 4)
void vq_mfma(const f16* __restrict__ A3, const f16* __restrict__ B3,
             const float* __restrict__ cn, u64* __restrict__ pk) {
    __shared__ f16 Bs[2][8192];   // [buf][16 slot][64 code][8]

    const int bid = blockIdx.x;
    const int nb  = bid >> 6;        // 0..15 (512-code groups)
    const int mb  = bid & 63;        // 0..63 (256-pixel tiles)
    const int m0  = mb * 256;
    const int n0  = nb * 512;
    const int t = threadIdx.x, lane = t & 63, w = t >> 6;
    const int l15 = lane & 15, l4 = lane >> 4;
    const int wrow = m0 + w * 64;    // wave's 64 rows

    float bm[16];                    // [m 4][r 4] packed (dist|slot) min
#pragma unroll
    for (int i = 0; i < 16; ++i) bm[i] = 3.0e38f;

    const f32x4 zero4 = {0.f, 0.f, 0.f, 0.f};

    // ---- prologue: A fragments from global (held in regs all block) ----
    f16x8 afAll[2][4];               // [K-slice group][m-block]
#pragma unroll
    for (int s = 0; s < 2; ++s)
#pragma unroll
        for (int m = 0; m < 4; ++m)
            afAll[s][m] = *(const f16x8*)
                &A3[((u64)(s * 4 + l4) * NPIX + wrow + m * 16 + l15) * 8];

    // ---- stage B(ns=0) into buf 0: 16 x 1KB instrs, 4 per wave ----
#pragma unroll
    for (int j = 0; j < 4; ++j) {
        int q = w * 4 + j;           // slot 0..15
        gld_lds16(B3 + ((u64)q * KC + n0 + lane) * 8, &Bs[0][q * 512]);
    }
    __syncthreads();                 // B(0) resident

    static const int sidx_t[4] = {0, 1, 0, 1};
    static const int sb_t[4]   = {0, 4, 8, 12};

#pragma unroll 1
    for (int ns = 0; ns < 8; ++ns) {
        const int nsub = n0 + ns * 64;
        const f16* bl = &Bs[ns & 1][0];

        // ---- issue next-ns B staging into the idle buffer ----
        if (ns < 7) {
            f16* bo = &Bs[(ns & 1) ^ 1][0];
#pragma unroll
            for (int j = 0; j < 4; ++j) {
                int q = w * 4 + j;
                gld_lds16(B3 + ((u64)q * KC + nsub + 64 + lane) * 8,
                          bo + q * 512);
            }
        }

        // ---- two n-halves: live acc is 4x2 (32 AGPR) ----
#pragma unroll
        for (int h = 0; h < 2; ++h) {
            f32x4 acc[4][2];
#pragma unroll
            for (int kt = 0; kt < 4; ++kt) {
                const int sb = sb_t[kt], si = sidx_t[kt];
                f16x8 bf[2];
#pragma unroll
                for (int n = 0; n < 2; ++n)
                    bf[n] = *(const f16x8*)
                        &bl[((sb + l4) * 64 + (h * 2 + n) * 16 + l15) * 8];
                if (kt == 0) {
#pragma unroll
                    for (int m = 0; m < 4; ++m)
#pragma unroll
                        for (int n = 0; n < 2; ++n)
                            acc[m][n] = __builtin_amdgcn_mfma_f32_16x16x32_f16(
                                afAll[si][m], bf[n], zero4, 0, 0, 0);
                } else {
#pragma unroll
                    for (int m = 0; m < 4; ++m)
#pragma unroll
                        for (int n = 0; n < 2; ++n)
                            acc[m][n] = __builtin_amdgcn_mfma_f32_16x16x32_f16(
                                afAll[si][m], bf[n], acc[m][n], 0, 0, 0);
                }
            }

            // ---- epilogue for this half: packed slot-in-mantissa min ----
            const int cb = nsub + h * 32 + l15;
            float cnv[2];
#pragma unroll
            for (int n = 0; n < 2; ++n) cnv[n] = cn[cb + n * 16];
#pragma unroll
            for (int m = 0; m < 4; ++m)
#pragma unroll
                for (int r = 0; r < 4; ++r) {
                    const int i = m * 4 + r;
                    float p0, p1;
                    {
                        float dist = fmaf(-2.f, acc[m][0][r], cnv[0]);
                        p0 = __uint_as_float(
                            (__float_as_uint(dist) & 0xFFFFFFE0u)
                            | (uint32_t)(ns * 4 + h * 2));
                        dist = fmaf(-2.f, acc[m][1][r], cnv[1]);
                        p1 = __uint_as_float(
                            (__float_as_uint(dist) & 0xFFFFFFE0u)
                            | (uint32_t)(ns * 4 + h * 2 + 1));
                    }
                    bm[i] = fminf(fminf(bm[i], p0), p1);   // v_min3
                }
        }

        if (ns < 7) __syncthreads();   // staged B(ns+1) resident; bufs swap
    }

    // ---- unpack slot -> col; 16-lane reduce; write pk ----
    const u64 pkb = (u64)nb * NPIX;
#pragma unroll
    for (int m = 0; m < 4; ++m)
#pragma unroll
        for (int r = 0; r < 4; ++r) {
            float d = bm[m * 4 + r];
            uint32_t slot = __float_as_uint(d) & 31u;
            int c = n0 + (int)(slot >> 2) * 64 + (int)(slot & 3) * 16 + l15;
#pragma unroll
            for (int off = 1; off < 16; off <<= 1) {
                float od = __shfl_xor(d, off, 64);
                int   oc = __shfl_xor(c, off, 64);
                if (od < d || (od == d && oc < c)) { d = od; c = oc; }
            }
            if (l15 == 0) {
                int row = wrow + m * 16 + l4 * 4 + r;
                pk[pkb + row] = ((u64)__float_as_uint(d) << 32) | (u64)c;
            }
        }
}

// ---------------------------------------------------------------------------
// Fused pick + gather. 256 blocks x 256 threads. First 64 threads pick
// their row (top-2 from 16 group minima, exact fp32 recompute, strict
// argmin semantics, write dmin + ind), hand indices via LDS; then all 4
// waves write the 64x64 quant stripe with coalesced stores.
// ---------------------------------------------------------------------------
__global__ __launch_bounds__(256)
void vq_pick_gather(const float* __restrict__ x, const float* __restrict__ em,
                    const float* __restrict__ cn, const u64* __restrict__ pk,
                    float* __restrict__ out) {
    __shared__ int ibs[64];
    const int tid = threadIdx.x;
    const int nb  = blockIdx.x;

    if (tid < 64) {
        int n = nb * 64 + tid;
        u64 b1 = ~0ull, b2 = ~0ull;
#pragma unroll 4
        for (int g = 0; g < 16; ++g) {
            u64 v = pk[(u64)g * NPIX + n];
            if (v < b1)      { b2 = b1; b1 = v; }
            else if (v < b2) { b2 = v; }
        }
        int i1 = (int)(b1 & 0xffffffffull);
        int i2 = (int)(b2 & 0xffffffffull);

        float rn = 0.f, dot1 = 0.f, dot2 = 0.f;
#pragma unroll 8
        for (int d = 0; d < DD; ++d) {
            float xv = x[d * NPIX + n];
            rn   = fmaf(xv, xv, rn);
            dot1 = fmaf(xv, em[d * EMS + i1], dot1);
            dot2 = fmaf(xv, em[d * EMS + i2], dot2);
        }
        float D1 = rn + (cn[i1] - 1024.f) - 2.f * dot1;
        float D2 = rn + (cn[i2] - 1024.f) - 2.f * dot2;
        int bi; float db;
        if (D2 < D1 || (D2 == D1 && i2 < i1)) { bi = i2; db = D2; }
        else                                  { bi = i1; db = D1; }

        out[OUT_DMIN + n] = db;
        out[OUT_IND  + n] = (float)bi;
        ibs[tid] = bi;
    }
    __syncthreads();

    const int nn = tid & 63;          // n within block
    const int d0 = (tid >> 6) * 16;   // 4 waves x 16 d rows
    const int n  = nb * 64 + nn;
    const int bi = ibs[nn];
#pragma unroll
    for (int j = 0; j < 16; ++j) {
        int d = d0 + j;
        out[OUT_QUANT + (u64)d * NPIX + n] = em[(u64)d * EMS + bi];
    }
}

// ---------------------------------------------------------------------------
extern "C" void kernel_launch(void* const* d_in, const int* in_sizes, int n_in,
                              void* d_out, int out_size, void* d_ws, size_t ws_size,
                              hipStream_t stream) {
    const float* x     = (const float*)d_in[0];   // [1,64,128,128]
    const float* embed = (const float*)d_in[1];   // [64,8193]
    const int*   cnt   = (const int*)d_in[2];     // [8192]
    float* out = (float*)d_out;

    // ws layout: A3 2MB | B3 2MB | pk 2MB | cn 32KB  (6.03 MB)
    f16*   A3 = (f16*)d_ws;
    f16*   B3 = (f16*)((char*)d_ws + (size_t)2 * 1024 * 1024);
    u64*   pk = (u64*)((char*)d_ws + (size_t)4 * 1024 * 1024);
    float* cn = (float*)((char*)d_ws + (size_t)6 * 1024 * 1024);

    vq_prep<<<768, 256, 0, stream>>>(x, embed, cnt, A3, B3, cn);
    vq_mfma<<<64 * 16, 256, 0, stream>>>(A3, B3, cn, pk);
    vq_pick_gather<<<NPIX / 64, 256, 0, stream>>>(x, embed, cn, pk, out);
}

// Round 24
// 64.100 us; speedup vs baseline: 1.1803x; 1.1803x over previous
//
#include <hip/hip_runtime.h>
#include <stdint.h>

#define NPIX   16384
#define KC     8192
#define DD     64
#define EMS    8193          // embed row stride (K+1)
#define OUT_QUANT 0
#define OUT_DMIN  1048576
#define OUT_IND   (1048576 + 16384)

typedef _Float16 f16;
typedef _Float16 f16x8 __attribute__((ext_vector_type(8)));
typedef float    f32x4 __attribute__((ext_vector_type(4)));
typedef unsigned long long u64;

// async global->LDS, 16B/lane; dest = wave-uniform base (+lane*16 by HW)
__device__ __forceinline__ void gld_lds16(const void* g, void* l) {
    __builtin_amdgcn_global_load_lds(
        (const __attribute__((address_space(1))) uint32_t*)g,
        (__attribute__((address_space(3))) uint32_t*)l, 16, 0, 0);
}

// ---------------------------------------------------------------------------
// Fused prep, parallelized over (slot, element): 768 blocks.
// Blocks 0..511   : x -> f16 HI A3[8][NPIX][8]   (thread = one (s,n))
// Blocks 512..767 : embed -> f16 hi/lo B3[16][KC][8] + f32 transposed
//                   emT[k][64] (values already in regs -- free); the s==0
//                   slice also computes masked +1024-biased norms.
// ---------------------------------------------------------------------------
__global__ __launch_bounds__(256)
void vq_prep(const float* __restrict__ x, const float* __restrict__ em,
             const int* __restrict__ cnt,
             f16* __restrict__ A3, f16* __restrict__ B3,
             float* __restrict__ cn, float* __restrict__ emT) {
    const int b = blockIdx.x;
    if (b < 512) {
        int id = b * 256 + threadIdx.x;      // (s,n)
        int n = id & (NPIX - 1);
        int s = id >> 14;
        f16x8 hv;
#pragma unroll
        for (int j = 0; j < 8; ++j)
            hv[j] = (f16)x[(s * 8 + j) * NPIX + n];
        *(f16x8*)&A3[((u64)s * NPIX + n) * 8] = hv;
    } else {
        int id = (b - 512) * 256 + threadIdx.x;   // (s,k)
        int k = id & (KC - 1);
        int s = id >> 13;
        float v[8];
        f16x8 hv, lv;
#pragma unroll
        for (int j = 0; j < 8; ++j) {
            v[j] = em[(s * 8 + j) * EMS + k];
            f16 h = (f16)v[j];
            hv[j] = h;
            lv[j] = (f16)(v[j] - (float)h);
        }
        *(f16x8*)&B3[((u64)(s)     * KC + k) * 8] = hv;
        *(f16x8*)&B3[((u64)(s + 8) * KC + k) * 8] = lv;
        *(float4*)&emT[(u64)k * 64 + s * 8]     =
            make_float4(v[0], v[1], v[2], v[3]);
        *(float4*)&emT[(u64)k * 64 + s * 8 + 4] =
            make_float4(v[4], v[5], v[6], v[7]);
        if (s == 0) {
            float s2 = 0.f;
#pragma unroll
            for (int d = 0; d < DD; ++d) {
                float vv = em[d * EMS + k];
                s2 = fmaf(vv, vv, s2);
            }
            cn[k] = (cnt[k] < 1) ? 1.0e30f : (s2 + 1024.f);
        }
    }
}

// ---------------------------------------------------------------------------
// MFMA distance GEMM + fused per-block argmin, 2-phase pipelined (R18
// verbatim -- proven 45.8us, VGPR 48 + 32 AGPR, 4 blocks/CU, no spill).
// Product: Xh.E = Xh.Eh + Xh.El  -> 4 K-steps of 32 (K=128).
// Block: 128 pixels x 512 codes, 8 ns-subtiles of 64 codes. Wave w owns
// rows w*32..+31, all cols -> one pk group per block (16 total).
// A-fragments in regs from one-time global prologue. B double-buffered in
// LDS (2 x 16 KB). Epilogue: packed slot-in-mantissa fminf min (3 VALU per
// candidate); mantissa corruption <=0.008 covered by exact top-2 recompute;
// slot order == col order preserves the ascending-col strict-< tie-break.
// ---------------------------------------------------------------------------
__global__ __launch_bounds__(256, 4)
void vq_mfma(const f16* __restrict__ A3, const f16* __restrict__ B3,
             const float* __restrict__ cn, u64* __restrict__ pk) {
    __shared__ f16 Bs[2][8192];   // [buf][16 slot][64 code][8]

    const int bid = blockIdx.x;
    const int nb  = bid >> 7;        // 0..15 (512-code groups)
    const int mb  = bid & 127;       // 0..127 (128-pixel tiles)
    const int m0  = mb * 128;
    const int n0  = nb * 512;
    const int t = threadIdx.x, lane = t & 63, w = t >> 6;
    const int l15 = lane & 15, l4 = lane >> 4;
    const int wrow = m0 + w * 32;    // wave's 32 rows

    float bm[8];                     // [m 2][r 4] packed (dist|slot) min
#pragma unroll
    for (int i = 0; i < 8; ++i) bm[i] = 3.0e38f;

    const f32x4 zero4 = {0.f, 0.f, 0.f, 0.f};

    // ---- prologue: A fragments from global (held in regs all block) ----
    f16x8 afAll[2][2];               // [sa group][m]
#pragma unroll
    for (int s = 0; s < 2; ++s)
#pragma unroll
        for (int m = 0; m < 2; ++m)
            afAll[s][m] = *(const f16x8*)
                &A3[((u64)(s * 4 + l4) * NPIX + wrow + m * 16 + l15) * 8];

    // ---- stage B(ns=0) into buf 0: 16 x 1KB instrs, 4 per wave ----
#pragma unroll
    for (int j = 0; j < 4; ++j) {
        int q = w * 4 + j;           // slot 0..15
        gld_lds16(B3 + ((u64)q * KC + n0 + lane) * 8, &Bs[0][q * 512]);
    }
    __syncthreads();                 // B(0) resident

    static const int sidx_t[4] = {0, 1, 0, 1};
    static const int sb_t[4]   = {0, 4, 8, 12};

#pragma unroll 1
    for (int ns = 0; ns < 8; ++ns) {
        const int nsub = n0 + ns * 64;
        const f16* bl = &Bs[ns & 1][0];

        // ---- issue next-ns B staging into the idle buffer ----
        if (ns < 7) {
            f16* bo = &Bs[(ns & 1) ^ 1][0];
#pragma unroll
            for (int j = 0; j < 4; ++j) {
                int q = w * 4 + j;
                gld_lds16(B3 + ((u64)q * KC + nsub + 64 + lane) * 8,
                          bo + q * 512);
            }
        }

        f32x4 acc[2][4];
#pragma unroll
        for (int kt = 0; kt < 4; ++kt) {
            const int sb = sb_t[kt], si = sidx_t[kt];
            f16x8 bf[4];
#pragma unroll
            for (int n = 0; n < 4; ++n)
                bf[n] = *(const f16x8*)
                    &bl[((sb + l4) * 64 + n * 16 + l15) * 8];
            if (kt == 0) {
#pragma unroll
                for (int m = 0; m < 2; ++m)
#pragma unroll
                    for (int n = 0; n < 4; ++n)
                        acc[m][n] = __builtin_amdgcn_mfma_f32_16x16x32_f16(
                            afAll[si][m], bf[n], zero4, 0, 0, 0);
            } else {
#pragma unroll
                for (int m = 0; m < 2; ++m)
#pragma unroll
                    for (int n = 0; n < 4; ++n)
                        acc[m][n] = __builtin_amdgcn_mfma_f32_16x16x32_f16(
                            afAll[si][m], bf[n], acc[m][n], 0, 0, 0);
            }
        }

        // ---- epilogue: dist = cn(biased) - 2*dot; packed min ----
        const int cb = nsub + l15;
        float cnv[4];
#pragma unroll
        for (int n = 0; n < 4; ++n) cnv[n] = cn[cb + n * 16];
#pragma unroll
        for (int m = 0; m < 2; ++m)
#pragma unroll
            for (int r = 0; r < 4; ++r) {
                const int i = m * 4 + r;
                float p[4];
#pragma unroll
                for (int n = 0; n < 4; ++n) {
                    float dist = fmaf(-2.f, acc[m][n][r], cnv[n]);
                    p[n] = __uint_as_float(
                        (__float_as_uint(dist) & 0xFFFFFFE0u)
                        | (uint32_t)(ns * 4 + n));
                }
                float q = fminf(fminf(p[0], p[1]), p[2]);   // v_min3
                bm[i] = fminf(fminf(bm[i], q), p[3]);       // v_min3
            }

        if (ns < 7) __syncthreads();   // staged B(ns+1) resident; bufs swap
    }

    // ---- unpack slot -> col; 16-lane reduce; write pk ----
    const u64 pkb = (u64)nb * NPIX;
#pragma unroll
    for (int m = 0; m < 2; ++m)
#pragma unroll
        for (int r = 0; r < 4; ++r) {
            float d = bm[m * 4 + r];
            uint32_t slot = __float_as_uint(d) & 31u;
            int c = n0 + (int)(slot >> 2) * 64 + (int)(slot & 3) * 16 + l15;
#pragma unroll
            for (int off = 1; off < 16; off <<= 1) {
                float od = __shfl_xor(d, off, 64);
                int   oc = __shfl_xor(c, off, 64);
                if (od < d || (od == d && oc < c)) { d = od; c = oc; }
            }
            if (l15 == 0) {
                int row = wrow + m * 16 + l4 * 4 + r;
                pk[pkb + row] = ((u64)__float_as_uint(d) << 32) | (u64)c;
            }
        }
}

// ---------------------------------------------------------------------------
// Fused pick + gather, emT-accelerated. 256 blocks x 256 threads.
// First 64 threads pick their row: top-2 from 16 group minima, exact fp32
// recompute via CONTIGUOUS float4 emT rows (16 loads/candidate, was 64
// scattered), strict argmin semantics, write dmin + ind; indices via LDS.
// Then all threads gather: thread (nn, dg) reads emT[bi] as 4 x float4
// and writes 16 coalesced out elements.
// ---------------------------------------------------------------------------
__global__ __launch_bounds__(256)
void vq_pick_gather(const float* __restrict__ x, const float* __restrict__ emT,
                    const float* __restrict__ cn, const u64* __restrict__ pk,
                    float* __restrict__ out) {
    __shared__ int ibs[64];
    const int tid = threadIdx.x;
    const int nb  = blockIdx.x;

    if (tid < 64) {
        int n = nb * 64 + tid;
        u64 b1 = ~0ull, b2 = ~0ull;
#pragma unroll 4
        for (int g = 0; g < 16; ++g) {
            u64 v = pk[(u64)g * NPIX + n];
            if (v < b1)      { b2 = b1; b1 = v; }
            else if (v < b2) { b2 = v; }
        }
        int i1 = (int)(b1 & 0xffffffffull);
        int i2 = (int)(b2 & 0xffffffffull);

        const float4* e1 = (const float4*)&emT[(u64)i1 * 64];
        const float4* e2 = (const float4*)&emT[(u64)i2 * 64];
        float rn = 0.f, dot1 = 0.f, dot2 = 0.f;
#pragma unroll
        for (int j = 0; j < 16; ++j) {
            float4 xv = make_float4(x[(j * 4 + 0) * NPIX + n],
                                    x[(j * 4 + 1) * NPIX + n],
                                    x[(j * 4 + 2) * NPIX + n],
                                    x[(j * 4 + 3) * NPIX + n]);
            float4 a = e1[j], b = e2[j];
            rn   = fmaf(xv.x, xv.x, fmaf(xv.y, xv.y,
                   fmaf(xv.z, xv.z, fmaf(xv.w, xv.w, rn))));
            dot1 = fmaf(xv.x, a.x, fmaf(xv.y, a.y,
                   fmaf(xv.z, a.z, fmaf(xv.w, a.w, dot1))));
            dot2 = fmaf(xv.x, b.x, fmaf(xv.y, b.y,
                   fmaf(xv.z, b.z, fmaf(xv.w, b.w, dot2))));
        }
        float D1 = rn + (cn[i1] - 1024.f) - 2.f * dot1;
        float D2 = rn + (cn[i2] - 1024.f) - 2.f * dot2;
        int bi; float db;
        if (D2 < D1 || (D2 == D1 && i2 < i1)) { bi = i2; db = D2; }
        else                                  { bi = i1; db = D1; }

        out[OUT_DMIN + n] = db;
        out[OUT_IND  + n] = (float)bi;
        ibs[tid] = bi;
    }
    __syncthreads();

    const int nn = tid & 63;          // n within block
    const int dg = tid >> 6;          // 0..3 -> 16 d rows each
    const int n  = nb * 64 + nn;
    const int bi = ibs[nn];
    const float4* ev = (const float4*)&emT[(u64)bi * 64 + dg * 16];
#pragma unroll
    for (int q = 0; q < 4; ++q) {
        float4 v = ev[q];
        int d = dg * 16 + q * 4;
        out[OUT_QUANT + (u64)(d + 0) * NPIX + n] = v.x;
        out[OUT_QUANT + (u64)(d + 1) * NPIX + n] = v.y;
        out[OUT_QUANT + (u64)(d + 2) * NPIX + n] = v.z;
        out[OUT_QUANT + (u64)(d + 3) * NPIX + n] = v.w;
    }
}

// ---------------------------------------------------------------------------
extern "C" void kernel_launch(void* const* d_in, const int* in_sizes, int n_in,
                              void* d_out, int out_size, void* d_ws, size_t ws_size,
                              hipStream_t stream) {
    const float* x     = (const float*)d_in[0];   // [1,64,128,128]
    const float* embed = (const float*)d_in[1];   // [64,8193]
    const int*   cnt   = (const int*)d_in[2];     // [8192]
    float* out = (float*)d_out;

    // ws layout: A3 2MB | B3 2MB | pk 2MB | emT 4MB-slot | cn 32KB (8.03 MB)
    f16*   A3  = (f16*)d_ws;
    f16*   B3  = (f16*)((char*)d_ws + (size_t)2 * 1024 * 1024);
    u64*   pk  = (u64*)((char*)d_ws + (size_t)4 * 1024 * 1024);
    float* emT = (float*)((char*)d_ws + (size_t)6 * 1024 * 1024);
    float* cn  = (float*)((char*)d_ws + (size_t)8 * 1024 * 1024);

    vq_prep<<<768, 256, 0, stream>>>(x, embed, cnt, A3, B3, cn, emT);
    vq_mfma<<<128 * 16, 256, 0, stream>>>(A3, B3, cn, pk);
    vq_pick_gather<<<NPIX / 64, 256, 0, stream>>>(x, emT, cn, pk, out);
}

// Round 25
// 57.679 us; speedup vs baseline: 1.3117x; 1.1113x over previous
//
#include <hip/hip_runtime.h>
#include <stdint.h>

#define NPIX   16384
#define KC     8192
#define DD     64
#define EMS    8193          // embed row stride (K+1)
#define OUT_QUANT 0
#define OUT_DMIN  1048576
#define OUT_IND   (1048576 + 16384)

typedef _Float16 f16;
typedef _Float16 f16x8 __attribute__((ext_vector_type(8)));
typedef float    f32x4 __attribute__((ext_vector_type(4)));
typedef unsigned long long u64;

// async global->LDS, 16B/lane; dest = wave-uniform base (+lane*16 by HW)
__device__ __forceinline__ void gld_lds16(const void* g, void* l) {
    __builtin_amdgcn_global_load_lds(
        (const __attribute__((address_space(1))) uint32_t*)g,
        (__attribute__((address_space(3))) uint32_t*)l, 16, 0, 0);
}

// ---------------------------------------------------------------------------
// Prep (embed only -- x is converted in-kernel by vq_mfma now): 256 blocks.
// Thread = one (s,k): embed -> f16 hi/lo B3[16][KC][8] + f32 transposed
// emT[k][64]; the s==0 slice also computes masked +1024-biased norms.
// ---------------------------------------------------------------------------
__global__ __launch_bounds__(256)
void vq_prep(const float* __restrict__ em, const int* __restrict__ cnt,
             f16* __restrict__ B3, float* __restrict__ cn,
             float* __restrict__ emT) {
    int id = blockIdx.x * 256 + threadIdx.x;   // (s,k)
    int k = id & (KC - 1);
    int s = id >> 13;
    float v[8];
    f16x8 hv, lv;
#pragma unroll
    for (int j = 0; j < 8; ++j) {
        v[j] = em[(s * 8 + j) * EMS + k];
        f16 h = (f16)v[j];
        hv[j] = h;
        lv[j] = (f16)(v[j] - (float)h);
    }
    *(f16x8*)&B3[((u64)(s)     * KC + k) * 8] = hv;
    *(f16x8*)&B3[((u64)(s + 8) * KC + k) * 8] = lv;
    *(float4*)&emT[(u64)k * 64 + s * 8]     =
        make_float4(v[0], v[1], v[2], v[3]);
    *(float4*)&emT[(u64)k * 64 + s * 8 + 4] =
        make_float4(v[4], v[5], v[6], v[7]);
    if (s == 0) {
        float s2 = 0.f;
#pragma unroll
        for (int d = 0; d < DD; ++d) {
            float vv = em[d * EMS + k];
            s2 = fmaf(vv, vv, s2);
        }
        cn[k] = (cnt[k] < 1) ? 1.0e30f : (s2 + 1024.f);
    }
}

// ---------------------------------------------------------------------------
// MFMA distance GEMM + fused per-block argmin, 2-phase pipelined (R18
// structure -- proven 45.8us, 4 blocks/CU, no spill). A-fragments are now
// built DIRECTLY from x (32 one-time scalar loads + f16 cvt per thread,
// issued after the B-staging gld_lds so the latency overlaps the drain) --
// the A3 intermediate and its 512 prep blocks are gone.
// Product: Xh.E = Xh.Eh + Xh.El  -> 4 K-steps of 32 (K=128).
// Block: 128 pixels x 512 codes, 8 ns-subtiles of 64 codes. Wave w owns
// rows w*32..+31, all cols -> one pk group per block (16 total).
// Epilogue: packed slot-in-mantissa fminf min (3 VALU/candidate); mantissa
// corruption <=0.008 covered by exact top-2 recompute; slot order == col
// order preserves the ascending-col strict-< tie-break.
// ---------------------------------------------------------------------------
__global__ __launch_bounds__(256, 4)
void vq_mfma(const float* __restrict__ x, const f16* __restrict__ B3,
             const float* __restrict__ cn, u64* __restrict__ pk) {
    __shared__ f16 Bs[2][8192];   // [buf][16 slot][64 code][8]

    const int bid = blockIdx.x;
    const int nb  = bid >> 7;        // 0..15 (512-code groups)
    const int mb  = bid & 127;       // 0..127 (128-pixel tiles)
    const int m0  = mb * 128;
    const int n0  = nb * 512;
    const int t = threadIdx.x, lane = t & 63, w = t >> 6;
    const int l15 = lane & 15, l4 = lane >> 4;
    const int wrow = m0 + w * 32;    // wave's 32 rows

    float bm[8];                     // [m 2][r 4] packed (dist|slot) min
#pragma unroll
    for (int i = 0; i < 8; ++i) bm[i] = 3.0e38f;

    const f32x4 zero4 = {0.f, 0.f, 0.f, 0.f};

    // ---- stage B(ns=0) into buf 0 FIRST (latency overlapped below) ----
#pragma unroll
    for (int j = 0; j < 4; ++j) {
        int q = w * 4 + j;           // slot 0..15
        gld_lds16(B3 + ((u64)q * KC + n0 + lane) * 8, &Bs[0][q * 512]);
    }

    // ---- A fragments straight from x: f32 load + f16 convert (one-time,
    //      coalesced 64B per l15 group, L3-resident) ----
    f16x8 afAll[2][2];               // [sa group][m]
#pragma unroll
    for (int s = 0; s < 2; ++s)
#pragma unroll
        for (int m = 0; m < 2; ++m) {
            const float* xp = x + (u64)(s * 4 + l4) * 8 * NPIX
                                + wrow + m * 16 + l15;
            f16x8 hv;
#pragma unroll
            for (int j = 0; j < 8; ++j)
                hv[j] = (f16)xp[(u64)j * NPIX];
            afAll[s][m] = hv;
        }
    __syncthreads();                 // B(0) resident

    static const int sidx_t[4] = {0, 1, 0, 1};
    static const int sb_t[4]   = {0, 4, 8, 12};

#pragma unroll 1
    for (int ns = 0; ns < 8; ++ns) {
        const int nsub = n0 + ns * 64;
        const f16* bl = &Bs[ns & 1][0];

        // ---- issue next-ns B staging into the idle buffer ----
        if (ns < 7) {
            f16* bo = &Bs[(ns & 1) ^ 1][0];
#pragma unroll
            for (int j = 0; j < 4; ++j) {
                int q = w * 4 + j;
                gld_lds16(B3 + ((u64)q * KC + nsub + 64 + lane) * 8,
                          bo + q * 512);
            }
        }

        f32x4 acc[2][4];
#pragma unroll
        for (int kt = 0; kt < 4; ++kt) {
            const int sb = sb_t[kt], si = sidx_t[kt];
            f16x8 bf[4];
#pragma unroll
            for (int n = 0; n < 4; ++n)
                bf[n] = *(const f16x8*)
                    &bl[((sb + l4) * 64 + n * 16 + l15) * 8];
            if (kt == 0) {
#pragma unroll
                for (int m = 0; m < 2; ++m)
#pragma unroll
                    for (int n = 0; n < 4; ++n)
                        acc[m][n] = __builtin_amdgcn_mfma_f32_16x16x32_f16(
                            afAll[si][m], bf[n], zero4, 0, 0, 0);
            } else {
#pragma unroll
                for (int m = 0; m < 2; ++m)
#pragma unroll
                    for (int n = 0; n < 4; ++n)
                        acc[m][n] = __builtin_amdgcn_mfma_f32_16x16x32_f16(
                            afAll[si][m], bf[n], acc[m][n], 0, 0, 0);
            }
        }

        // ---- epilogue: dist = cn(biased) - 2*dot; packed min ----
        const int cb = nsub + l15;
        float cnv[4];
#pragma unroll
        for (int n = 0; n < 4; ++n) cnv[n] = cn[cb + n * 16];
#pragma unroll
        for (int m = 0; m < 2; ++m)
#pragma unroll
            for (int r = 0; r < 4; ++r) {
                const int i = m * 4 + r;
                float p[4];
#pragma unroll
                for (int n = 0; n < 4; ++n) {
                    float dist = fmaf(-2.f, acc[m][n][r], cnv[n]);
                    p[n] = __uint_as_float(
                        (__float_as_uint(dist) & 0xFFFFFFE0u)
                        | (uint32_t)(ns * 4 + n));
                }
                float q = fminf(fminf(p[0], p[1]), p[2]);   // v_min3
                bm[i] = fminf(fminf(bm[i], q), p[3]);       // v_min3
            }

        if (ns < 7) __syncthreads();   // staged B(ns+1) resident; bufs swap
    }

    // ---- unpack slot -> col; 16-lane reduce; write pk ----
    const u64 pkb = (u64)nb * NPIX;
#pragma unroll
    for (int m = 0; m < 2; ++m)
#pragma unroll
        for (int r = 0; r < 4; ++r) {
            float d = bm[m * 4 + r];
            uint32_t slot = __float_as_uint(d) & 31u;
            int c = n0 + (int)(slot >> 2) * 64 + (int)(slot & 3) * 16 + l15;
#pragma unroll
            for (int off = 1; off < 16; off <<= 1) {
                float od = __shfl_xor(d, off, 64);
                int   oc = __shfl_xor(c, off, 64);
                if (od < d || (od == d && oc < c)) { d = od; c = oc; }
            }
            if (l15 == 0) {
                int row = wrow + m * 16 + l4 * 4 + r;
                pk[pkb + row] = ((u64)__float_as_uint(d) << 32) | (u64)c;
            }
        }
}

// ---------------------------------------------------------------------------
// Fused pick + gather, emT-accelerated. 256 blocks x 256 threads.
// First 64 threads pick their row: top-2 from 16 group minima, exact fp32
// recompute via contiguous float4 emT rows, strict argmin semantics, write
// dmin + ind; indices via LDS. Then all threads gather: thread (nn, dg)
// reads emT[bi] as 4 x float4 and writes 16 coalesced out elements.
// ---------------------------------------------------------------------------
__global__ __launch_bounds__(256)
void vq_pick_gather(const float* __restrict__ x, const float* __restrict__ emT,
                    const float* __restrict__ cn, const u64* __restrict__ pk,
                    float* __restrict__ out) {
    __shared__ int ibs[64];
    const int tid = threadIdx.x;
    const int nb  = blockIdx.x;

    if (tid < 64) {
        int n = nb * 64 + tid;
        u64 b1 = ~0ull, b2 = ~0ull;
#pragma unroll 4
        for (int g = 0; g < 16; ++g) {
            u64 v = pk[(u64)g * NPIX + n];
            if (v < b1)      { b2 = b1; b1 = v; }
            else if (v < b2) { b2 = v; }
        }
        int i1 = (int)(b1 & 0xffffffffull);
        int i2 = (int)(b2 & 0xffffffffull);

        const float4* e1 = (const float4*)&emT[(u64)i1 * 64];
        const float4* e2 = (const float4*)&emT[(u64)i2 * 64];
        float rn = 0.f, dot1 = 0.f, dot2 = 0.f;
#pragma unroll
        for (int j = 0; j < 16; ++j) {
            float4 xv = make_float4(x[(j * 4 + 0) * NPIX + n],
                                    x[(j * 4 + 1) * NPIX + n],
                                    x[(j * 4 + 2) * NPIX + n],
                                    x[(j * 4 + 3) * NPIX + n]);
            float4 a = e1[j], b = e2[j];
            rn   = fmaf(xv.x, xv.x, fmaf(xv.y, xv.y,
                   fmaf(xv.z, xv.z, fmaf(xv.w, xv.w, rn))));
            dot1 = fmaf(xv.x, a.x, fmaf(xv.y, a.y,
                   fmaf(xv.z, a.z, fmaf(xv.w, a.w, dot1))));
            dot2 = fmaf(xv.x, b.x, fmaf(xv.y, b.y,
                   fmaf(xv.z, b.z, fmaf(xv.w, b.w, dot2))));
        }
        float D1 = rn + (cn[i1] - 1024.f) - 2.f * dot1;
        float D2 = rn + (cn[i2] - 1024.f) - 2.f * dot2;
        int bi; float db;
        if (D2 < D1 || (D2 == D1 && i2 < i1)) { bi = i2; db = D2; }
        else                                  { bi = i1; db = D1; }

        out[OUT_DMIN + n] = db;
        out[OUT_IND  + n] = (float)bi;
        ibs[tid] = bi;
    }
    __syncthreads();

    const int nn = tid & 63;          // n within block
    const int dg = tid >> 6;          // 0..3 -> 16 d rows each
    const int n  = nb * 64 + nn;
    const int bi = ibs[nn];
    const float4* ev = (const float4*)&emT[(u64)bi * 64 + dg * 16];
#pragma unroll
    for (int q = 0; q < 4; ++q) {
        float4 v = ev[q];
        int d = dg * 16 + q * 4;
        out[OUT_QUANT + (u64)(d + 0) * NPIX + n] = v.x;
        out[OUT_QUANT + (u64)(d + 1) * NPIX + n] = v.y;
        out[OUT_QUANT + (u64)(d + 2) * NPIX + n] = v.z;
        out[OUT_QUANT + (u64)(d + 3) * NPIX + n] = v.w;
    }
}

// ---------------------------------------------------------------------------
extern "C" void kernel_launch(void* const* d_in, const int* in_sizes, int n_in,
                              void* d_out, int out_size, void* d_ws, size_t ws_size,
                              hipStream_t stream) {
    const float* x     = (const float*)d_in[0];   // [1,64,128,128]
    const float* embed = (const float*)d_in[1];   // [64,8193]
    const int*   cnt   = (const int*)d_in[2];     // [8192]
    float* out = (float*)d_out;

    // ws layout: B3 2MB | pk 2MB | emT 2MB | cn 32KB  (6.03 MB)
    f16*   B3  = (f16*)d_ws;
    u64*   pk  = (u64*)((char*)d_ws + (size_t)2 * 1024 * 1024);
    float* emT = (float*)((char*)d_ws + (size_t)4 * 1024 * 1024);
    float* cn  = (float*)((char*)d_ws + (size_t)6 * 1024 * 1024);

    vq_prep<<<256, 256, 0, stream>>>(embed, cnt, B3, cn, emT);
    vq_mfma<<<128 * 16, 256, 0, stream>>>(x, B3, cn, pk);
    vq_pick_gather<<<NPIX / 64, 256, 0, stream>>>(x, emT, cn, pk, out);
}

// Round 26
// 43.681 us; speedup vs baseline: 1.7321x; 1.3205x over previous
//
#include <hip/hip_runtime.h>
#include <stdint.h>

#define NPIX   16384
#define KC     8192
#define DD     64
#define EMS    8193          // embed row stride (K+1)
#define OUT_QUANT 0
#define OUT_DMIN  1048576
#define OUT_IND   (1048576 + 16384)

typedef _Float16 f16;
typedef _Float16 f16x8 __attribute__((ext_vector_type(8)));
typedef float    f32x4 __attribute__((ext_vector_type(4)));
typedef unsigned long long u64;

// async global->LDS, 16B/lane; dest = wave-uniform base (+lane*16 by HW)
__device__ __forceinline__ void gld_lds16(const void* g, void* l) {
    __builtin_amdgcn_global_load_lds(
        (const __attribute__((address_space(1))) uint32_t*)g,
        (__attribute__((address_space(3))) uint32_t*)l, 16, 0, 0);
}

// ---------------------------------------------------------------------------
// Prep (embed only): 256 blocks, thread = one (s,k), s=0..7.
// embed -> f16 HI B3[8][KC][8] + f32 transposed emT[k][64]; the s==0 slice
// also computes masked +1024-biased norms. (The El low-half is no longer
// stored: K=64 product Xh.Eh only; error ~1e-2 incl. packing, covered by
// the exact fp32 top-2 recompute in pick.)
// ---------------------------------------------------------------------------
__global__ __launch_bounds__(256)
void vq_prep(const float* __restrict__ em, const int* __restrict__ cnt,
             f16* __restrict__ B3, float* __restrict__ cn,
             float* __restrict__ emT) {
    int id = blockIdx.x * 256 + threadIdx.x;   // (s,k)
    int k = id & (KC - 1);
    int s = id >> 13;
    float v[8];
    f16x8 hv;
#pragma unroll
    for (int j = 0; j < 8; ++j) {
        v[j] = em[(s * 8 + j) * EMS + k];
        hv[j] = (f16)v[j];
    }
    *(f16x8*)&B3[((u64)s * KC + k) * 8] = hv;
    *(float4*)&emT[(u64)k * 64 + s * 8]     =
        make_float4(v[0], v[1], v[2], v[3]);
    *(float4*)&emT[(u64)k * 64 + s * 8 + 4] =
        make_float4(v[4], v[5], v[6], v[7]);
    if (s == 0) {
        float s2 = 0.f;
#pragma unroll
        for (int d = 0; d < DD; ++d) {
            float vv = em[d * EMS + k];
            s2 = fmaf(vv, vv, s2);
        }
        cn[k] = (cnt[k] < 1) ? 1.0e30f : (s2 + 1024.f);
    }
}

// ---------------------------------------------------------------------------
// MFMA distance GEMM + fused per-block argmin, 2-phase pipelined (R18
// structure, K=64: product Xh.Eh only -> 2 K-steps of 32).
// Block: 128 pixels x 512 codes, 8 ns-subtiles of 64 codes. Wave w owns
// rows w*32..+31, all cols -> one pk group per block (16 total).
// A-fragments built directly from x (32 one-time scalar f32 loads + cvt,
// issued after the B-staging gld_lds so latency overlaps the drain).
// B double-buffered in LDS (2 x 8 KB). Epilogue: packed slot-in-mantissa
// fminf min (3 VALU/candidate); approx error (~1e-2 total) covered by the
// exact top-2 recompute; slot order == col order keeps strict-< tie-break.
// ---------------------------------------------------------------------------
__global__ __launch_bounds__(256, 4)
void vq_mfma(const float* __restrict__ x, const f16* __restrict__ B3,
             const float* __restrict__ cn, u64* __restrict__ pk) {
    __shared__ f16 Bs[2][4096];   // [buf][8 slot][64 code][8]

    const int bid = blockIdx.x;
    const int nb  = bid >> 7;        // 0..15 (512-code groups)
    const int mb  = bid & 127;       // 0..127 (128-pixel tiles)
    const int m0  = mb * 128;
    const int n0  = nb * 512;
    const int t = threadIdx.x, lane = t & 63, w = t >> 6;
    const int l15 = lane & 15, l4 = lane >> 4;
    const int wrow = m0 + w * 32;    // wave's 32 rows

    float bm[8];                     // [m 2][r 4] packed (dist|slot) min
#pragma unroll
    for (int i = 0; i < 8; ++i) bm[i] = 3.0e38f;

    const f32x4 zero4 = {0.f, 0.f, 0.f, 0.f};

    // ---- stage B(ns=0) into buf 0 FIRST (latency overlapped below) ----
#pragma unroll
    for (int j = 0; j < 2; ++j) {
        int q = w * 2 + j;           // slot 0..7
        gld_lds16(B3 + ((u64)q * KC + n0 + lane) * 8, &Bs[0][q * 512]);
    }

    // ---- A fragments straight from x: f32 load + f16 convert (one-time,
    //      coalesced 64B per l15 group, L3-resident) ----
    f16x8 afAll[2][2];               // [kt][m]
#pragma unroll
    for (int s = 0; s < 2; ++s)
#pragma unroll
        for (int m = 0; m < 2; ++m) {
            const float* xp = x + (u64)(s * 4 + l4) * 8 * NPIX
                                + wrow + m * 16 + l15;
            f16x8 hv;
#pragma unroll
            for (int j = 0; j < 8; ++j)
                hv[j] = (f16)xp[(u64)j * NPIX];
            afAll[s][m] = hv;
        }
    __syncthreads();                 // B(0) resident

#pragma unroll 1
    for (int ns = 0; ns < 8; ++ns) {
        const int nsub = n0 + ns * 64;
        const f16* bl = &Bs[ns & 1][0];

        // ---- issue next-ns B staging into the idle buffer ----
        if (ns < 7) {
            f16* bo = &Bs[(ns & 1) ^ 1][0];
#pragma unroll
            for (int j = 0; j < 2; ++j) {
                int q = w * 2 + j;
                gld_lds16(B3 + ((u64)q * KC + nsub + 64 + lane) * 8,
                          bo + q * 512);
            }
        }

        f32x4 acc[2][4];
#pragma unroll
        for (int kt = 0; kt < 2; ++kt) {
            const int sb = kt * 4;
            f16x8 bf[4];
#pragma unroll
            for (int n = 0; n < 4; ++n)
                bf[n] = *(const f16x8*)
                    &bl[((sb + l4) * 64 + n * 16 + l15) * 8];
            if (kt == 0) {
#pragma unroll
                for (int m = 0; m < 2; ++m)
#pragma unroll
                    for (int n = 0; n < 4; ++n)
                        acc[m][n] = __builtin_amdgcn_mfma_f32_16x16x32_f16(
                            afAll[0][m], bf[n], zero4, 0, 0, 0);
            } else {
#pragma unroll
                for (int m = 0; m < 2; ++m)
#pragma unroll
                    for (int n = 0; n < 4; ++n)
                        acc[m][n] = __builtin_amdgcn_mfma_f32_16x16x32_f16(
                            afAll[1][m], bf[n], acc[m][n], 0, 0, 0);
            }
        }

        // ---- epilogue: dist = cn(biased) - 2*dot; packed min ----
        const int cb = nsub + l15;
        float cnv[4];
#pragma unroll
        for (int n = 0; n < 4; ++n) cnv[n] = cn[cb + n * 16];
#pragma unroll
        for (int m = 0; m < 2; ++m)
#pragma unroll
            for (int r = 0; r < 4; ++r) {
                const int i = m * 4 + r;
                float p[4];
#pragma unroll
                for (int n = 0; n < 4; ++n) {
                    float dist = fmaf(-2.f, acc[m][n][r], cnv[n]);
                    p[n] = __uint_as_float(
                        (__float_as_uint(dist) & 0xFFFFFFE0u)
                        | (uint32_t)(ns * 4 + n));
                }
                float q = fminf(fminf(p[0], p[1]), p[2]);   // v_min3
                bm[i] = fminf(fminf(bm[i], q), p[3]);       // v_min3
            }

        if (ns < 7) __syncthreads();   // staged B(ns+1) resident; bufs swap
    }

    // ---- unpack slot -> col; 16-lane reduce; write pk ----
    const u64 pkb = (u64)nb * NPIX;
#pragma unroll
    for (int m = 0; m < 2; ++m)
#pragma unroll
        for (int r = 0; r < 4; ++r) {
            float d = bm[m * 4 + r];
            uint32_t slot = __float_as_uint(d) & 31u;
            int c = n0 + (int)(slot >> 2) * 64 + (int)(slot & 3) * 16 + l15;
#pragma unroll
            for (int off = 1; off < 16; off <<= 1) {
                float od = __shfl_xor(d, off, 64);
                int   oc = __shfl_xor(c, off, 64);
                if (od < d || (od == d && oc < c)) { d = od; c = oc; }
            }
            if (l15 == 0) {
                int row = wrow + m * 16 + l4 * 4 + r;
                pk[pkb + row] = ((u64)__float_as_uint(d) << 32) | (u64)c;
            }
        }
}

// ---------------------------------------------------------------------------
// Fused pick + gather, emT-accelerated. 256 blocks x 256 threads.
// First 64 threads pick their row: top-2 from 16 group minima, exact fp32
// recompute via contiguous float4 emT rows, strict argmin semantics, write
// dmin + ind; indices via LDS. Then all threads gather: thread (nn, dg)
// reads emT[bi] as 4 x float4 and writes 16 coalesced out elements.
// ---------------------------------------------------------------------------
__global__ __launch_bounds__(256)
void vq_pick_gather(const float* __restrict__ x, const float* __restrict__ emT,
                    const float* __restrict__ cn, const u64* __restrict__ pk,
                    float* __restrict__ out) {
    __shared__ int ibs[64];
    const int tid = threadIdx.x;
    const int nb  = blockIdx.x;

    if (tid < 64) {
        int n = nb * 64 + tid;
        u64 b1 = ~0ull, b2 = ~0ull;
#pragma unroll 4
        for (int g = 0; g < 16; ++g) {
            u64 v = pk[(u64)g * NPIX + n];
            if (v < b1)      { b2 = b1; b1 = v; }
            else if (v < b2) { b2 = v; }
        }
        int i1 = (int)(b1 & 0xffffffffull);
        int i2 = (int)(b2 & 0xffffffffull);

        const float4* e1 = (const float4*)&emT[(u64)i1 * 64];
        const float4* e2 = (const float4*)&emT[(u64)i2 * 64];
        float rn = 0.f, dot1 = 0.f, dot2 = 0.f;
#pragma unroll
        for (int j = 0; j < 16; ++j) {
            float4 xv = make_float4(x[(j * 4 + 0) * NPIX + n],
                                    x[(j * 4 + 1) * NPIX + n],
                                    x[(j * 4 + 2) * NPIX + n],
                                    x[(j * 4 + 3) * NPIX + n]);
            float4 a = e1[j], b = e2[j];
            rn   = fmaf(xv.x, xv.x, fmaf(xv.y, xv.y,
                   fmaf(xv.z, xv.z, fmaf(xv.w, xv.w, rn))));
            dot1 = fmaf(xv.x, a.x, fmaf(xv.y, a.y,
                   fmaf(xv.z, a.z, fmaf(xv.w, a.w, dot1))));
            dot2 = fmaf(xv.x, b.x, fmaf(xv.y, b.y,
                   fmaf(xv.z, b.z, fmaf(xv.w, b.w, dot2))));
        }
        float D1 = rn + (cn[i1] - 1024.f) - 2.f * dot1;
        float D2 = rn + (cn[i2] - 1024.f) - 2.f * dot2;
        int bi; float db;
        if (D2 < D1 || (D2 == D1 && i2 < i1)) { bi = i2; db = D2; }
        else                                  { bi = i1; db = D1; }

        out[OUT_DMIN + n] = db;
        out[OUT_IND  + n] = (float)bi;
        ibs[tid] = bi;
    }
    __syncthreads();

    const int nn = tid & 63;          // n within block
    const int dg = tid >> 6;          // 0..3 -> 16 d rows each
    const int n  = nb * 64 + nn;
    const int bi = ibs[nn];
    const float4* ev = (const float4*)&emT[(u64)bi * 64 + dg * 16];
#pragma unroll
    for (int q = 0; q < 4; ++q) {
        float4 v = ev[q];
        int d = dg * 16 + q * 4;
        out[OUT_QUANT + (u64)(d + 0) * NPIX + n] = v.x;
        out[OUT_QUANT + (u64)(d + 1) * NPIX + n] = v.y;
        out[OUT_QUANT + (u64)(d + 2) * NPIX + n] = v.z;
        out[OUT_QUANT + (u64)(d + 3) * NPIX + n] = v.w;
    }
}

// ---------------------------------------------------------------------------
extern "C" void kernel_launch(void* const* d_in, const int* in_sizes, int n_in,
                              void* d_out, int out_size, void* d_ws, size_t ws_size,
                              hipStream_t stream) {
    const float* x     = (const float*)d_in[0];   // [1,64,128,128]
    const float* embed = (const float*)d_in[1];   // [64,8193]
    const int*   cnt   = (const int*)d_in[2];     // [8192]
    float* out = (float*)d_out;

    // ws layout: B3 1MB | pk 2MB | emT 2MB | cn 32KB  (5.03 MB)
    f16*   B3  = (f16*)d_ws;
    u64*   pk  = (u64*)((char*)d_ws + (size_t)1 * 1024 * 1024);
    float* emT = (float*)((char*)d_ws + (size_t)3 * 1024 * 1024);
    float* cn  = (float*)((char*)d_ws + (size_t)5 * 1024 * 1024);

    vq_prep<<<256, 256, 0, stream>>>(embed, cnt, B3, cn, emT);
    vq_mfma<<<128 * 16, 256, 0, stream>>>(x, B3, cn, pk);
    vq_pick_gather<<<NPIX / 64, 256, 0, stream>>>(x, emT, cn, pk, out);
}